// Round 1
// 565.212 us; speedup vs baseline: 1.0927x; 1.0927x over previous
//
#include <hip/hip_runtime.h>
#include <cstdint>

// Problem constants
#define T_ 64
#define A_ 48
#define NP_ 3072      // T*A pairs
#define E_ 22
#define RAW_ 512
#define H_ 256
#define NACT_ 21
#define NTP_ 3
#define PV_ 3456      // padded virtual pair rows (27 tiles of 128)
#define RV_ 68096     // padded virtual entity rows (532 tiles of 128)
#define NDEAD_ 67584  // NP_*E_

typedef unsigned short u16;
typedef __attribute__((ext_vector_type(8))) short short8;
typedef __attribute__((ext_vector_type(4))) short short4v;
typedef __attribute__((ext_vector_type(4))) float floatx4;

// HW RNE f32->bf16 via v_cvt_pk_bf16_f32. Self-pair form (both srcs = x) is
// operand-order-proof: low 16 bits hold bf16(x) either way.
__device__ __forceinline__ u16 f2bf(float x) {
    unsigned r;
    asm("v_cvt_pk_bf16_f32 %0, %1, %1" : "=v"(r) : "v"(x));
    return (u16)r;
}
__device__ __forceinline__ float bf2f(u16 h) {
    return __uint_as_float(((unsigned)h) << 16);
}

// global -> LDS direct DMA, 16B per lane. LDS dest must be linear in lane
// order (wave-uniform base + lane*16); global src is per-lane (swizzlable).
typedef __attribute__((address_space(1))) const void* gp_t;
typedef __attribute__((address_space(3))) void* lp_t;
__device__ __forceinline__ void gload16(const void* g, void* l) {
    __builtin_amdgcn_global_load_lds((gp_t)g, (lp_t)l, 16, 0, 0);
}

// ---------------------------------------------------------------------------
// K_bucket: sniff dead dtype, count pairs per type, build bucketed pair list.
// wsI layout: [0]=mode, [1..3]=cnt, [4..6]=ps, [8..10]=rs,
//             [16..16+PV)=pairIdx, then prb[PV]
// ---------------------------------------------------------------------------
__global__ void k_bucket(const unsigned* __restrict__ deadRaw,
                         const int* __restrict__ hete, int* __restrict__ wsI)
{
    __shared__ int fl[2];
    __shared__ int sc[3], cur[3], sps[3], srs[3];
    int tid = threadIdx.x;
    if (tid < 2) fl[tid] = 0;
    if (tid < 3) { sc[tid] = 0; cur[tid] = 0; }
    __syncthreads();
    int ni = 0, nf = 0;
    for (int i = tid; i < 1024; i += 256) {
        unsigned w = deadRaw[i];
        if (w > 1u) ni = 1;
        if (w != 0u && w != 0x3F800000u) nf = 1;
    }
    if (ni) atomicOr(&fl[0], 1);
    if (nf) atomicOr(&fl[1], 1);
    for (int p = tid; p < NP_; p += 256) atomicAdd(&sc[hete[p]], 1);
    __syncthreads();
    if (tid == 0) {
        int c0 = sc[0], c1 = sc[1], c2 = sc[2];
        int p1 = (c0 + 127) & ~127;
        int p2 = p1 + ((c1 + 127) & ~127);
        sps[0] = 0; sps[1] = p1; sps[2] = p2;
        int r1 = (22 * c0 + 127) & ~127;
        int r2 = r1 + ((22 * c1 + 127) & ~127);
        srs[0] = 0; srs[1] = r1; srs[2] = r2;
        wsI[0] = fl[0] ? (fl[1] ? 2 : 1) : 0;  // 0=int32,1=float32,2=byte
        wsI[1] = c0; wsI[2] = c1; wsI[3] = c2;
        wsI[4] = 0; wsI[5] = p1; wsI[6] = p2;
        wsI[8] = 0; wsI[9] = r1; wsI[10] = r2;
    }
    __syncthreads();
    int* pairIdx = wsI + 16;
    int* prb = pairIdx + PV_;
    for (int pv = tid; pv < PV_; pv += 256) pairIdx[pv] = -1;
    __syncthreads();
    for (int p = tid; p < NP_; p += 256) {
        int t = hete[p];
        int pos = atomicAdd(&cur[t], 1);
        pairIdx[sps[t] + pos] = p;
    }
    for (int pv = tid; pv < PV_; pv += 256) {
        int t = (pv >= sps[1]) + (pv >= sps[2]);
        prb[pv] = srs[t] + 22 * (pv - sps[t]);
    }
}

__global__ void k_deadmask(const void* __restrict__ dead,
                           const int* __restrict__ wsI, float* __restrict__ dm)
{
    int i = blockIdx.x * 256 + threadIdx.x;
    if (i >= NDEAD_) return;
    int mode = wsI[0];
    bool d;
    if (mode == 0)      d = ((const int*)dead)[i] != 0;
    else if (mode == 1) d = ((const float*)dead)[i] != 0.f;
    else                d = ((const unsigned char*)dead)[i] != 0;
    dm[i] = d ? 0.f : 1.f;
}

// rowObs[rv] = obs row index for virtual row, or -1 (padding OR dead -> zero A row)
__global__ void k_rowobs(const int* __restrict__ cnt, const int* __restrict__ ps,
                         const int* __restrict__ rs, const int* __restrict__ pairIdx,
                         const float* __restrict__ dm, int* __restrict__ rowObs)
{
    int rv = blockIdx.x * 256 + threadIdx.x;
    if (rv >= RV_) return;
    int t = (rv >= rs[1]) + (rv >= rs[2]);
    int local = rv - rs[t];
    int out = -1;
    if (local < 22 * cnt[t]) {
        int pl = local / 22;
        int e = local - pl * 22;
        int p = pairIdx[ps[t] + pl];
        if (p >= 0) {
            int oi = p * 22 + e;
            if (dm[oi] != 0.f) out = oi;
        }
    }
    rowObs[rv] = out;
}

// ---------------------------------------------------------------------------
// k_wconv (fused, all 8 weight matrices): W[t][k][n] fp32 -> hi/lo bf16 [t][n][k]
// ---------------------------------------------------------------------------
struct WCA {
    const float* W[8]; u16* Hi[8]; u16* Lo[8]; int K[8]; int bs[9];
};
__global__ __launch_bounds__(256) void k_wconv(WCA a)
{
    int blk = blockIdx.x;
    int s = 0;
#pragma unroll
    for (int i = 1; i < 8; ++i) if (blk >= a.bs[i]) s = i;
    int lb = blk - a.bs[s];
    int K = a.K[s];
    int K8 = K >> 3;
    int kc = lb % K8;
    int t  = lb / K8;
    int n  = threadIdx.x;
    const float* w = a.W[s] + (long)t * K * 256 + n;
    short8 hv, lv;
#pragma unroll
    for (int j = 0; j < 8; ++j) {
        float x = w[(long)(kc * 8 + j) * 256];
        u16 hh = f2bf(x);
        hv[j] = (short)hh;
        lv[j] = (short)f2bf(x - bf2f(hh));
    }
    long o = ((long)t * 256 + n) * K + kc * 8;
    *(short8*)(a.Hi[s] + o) = hv;
    *(short8*)(a.Lo[s] + o) = lv;
}

// ---------------------------------------------------------------------------
// MFMA GEMM, bf16x3 split: C = op(A) @ B[type] + bias[type], optional relu.
// Tile 128x128, BK=32, 256 threads. B always via global_load_lds.
// AMODE 0: A pre-split bf16 hi/lo, global_load_lds (no gather).
// AMODE 1: A fp32 + row-gather+mask, reg-staged, HW cvt_pk split (P1a only).
// OUTS  0: fp32 C.   OUTS 1: C written as bf16 hi/lo pair (pre-split for
//          the consuming GEMM -- numerically identical to in-GEMM split).
// LDS: linear [128][32] shorts per array. gload_lds dest is linear; the
// 16B-slot XOR swizzle (slot ^ (row&3)) is applied on the per-lane GLOBAL
// source and on the ds_read_b128 frag address (both-sides rule, m173/m201).
// ---------------------------------------------------------------------------
struct GD {
    const void* Aa; const void* Ab;   // AMODE0: hi,lo u16; AMODE1: fp32, unused
    const u16* Bh; const u16* Bl;
    const float* bias;
    void* Ca; void* Cb;               // OUTS0: fp32, unused; OUTS1: hi,lo u16
    long lda; long ldc;
    int K; int coff;
};
struct GA4 { GD d[4]; };

template<int AMODE, bool RELU, int OUTS>
__global__ __launch_bounds__(256) void k_mgemm(
    GA4 ga, const int* __restrict__ rowIdx, const int* __restrict__ starts)
{
    __shared__ short Ah[128 * 32], Al[128 * 32], Bh[128 * 32], Bl[128 * 32];
    const int tid = threadIdx.x;
    const GD d = ga.d[blockIdx.z];
    const long rb = (long)blockIdx.x * 128;
    const int n0 = blockIdx.y * 128;
    const int t = (rb >= starts[0]) + (rb >= starts[1]);
    const int K = d.K;
    const long lda = d.lda;
    const u16* bhT = d.Bh + ((long)t * 256 + n0) * K;
    const u16* blT = d.Bl + ((long)t * 256 + n0) * K;
    const float* biasT = d.bias + (long)t * 256 + n0;

    // gload chunk mapping: chunk c in [0,512): row = c>>2, 16B slot = c&3
    const int cs = tid & 3;

    // AMODE1 reg-stage mapping: 4 iters of 32 rows x 32 k
    const int ar = tid >> 3;            // 0..31
    const int ac = (tid & 7) * 4;       // 0..28
    long arow[4]; float amask[4];
    const float* Afp = (const float*)d.Aa;
    if (AMODE == 1) {
#pragma unroll
        for (int it = 0; it < 4; ++it) {
            int r = 32 * it + ar;
            int i0 = rowIdx[rb + r];
            amask[it] = (i0 < 0) ? 0.f : 1.f;
            arow[it] = (i0 < 0) ? 0 : (long)i0 * lda;
        }
    }
    const u16* ahT = (const u16*)d.Aa;
    const u16* alT = (const u16*)d.Ab;

    // wave tiling
    const int wave = tid >> 6;
    const int lane = tid & 63;
    const int wr = (wave >> 1) * 64;
    const int wc = (wave & 1) * 64;
    const int lm = lane & 15;
    const int quad = lane >> 4;

    floatx4 acc[4][4];
#pragma unroll
    for (int i = 0; i < 4; ++i)
#pragma unroll
        for (int j = 0; j < 4; ++j) acc[i][j] = (floatx4){0.f, 0.f, 0.f, 0.f};

    for (int k0 = 0; k0 < K; k0 += 32) {
        float4 av[4];
        if (AMODE == 1) {   // issue global A loads before barrier (overlap MFMA)
#pragma unroll
            for (int it = 0; it < 4; ++it)
                av[it] = *(const float4*)(Afp + arow[it] + k0 + ac);
        }
        __syncthreads();    // all waves done reading LDS tile of prev step
        // B: direct global->LDS (2 issues x 4KB per array)
#pragma unroll
        for (int i = 0; i < 2; ++i) {
            int c = i * 256 + tid;
            int r = c >> 2;
            long go = (long)r * K + k0 + ((cs ^ (r & 3)) << 3);
            gload16(bhT + go, &Bh[c << 3]);
            gload16(blT + go, &Bl[c << 3]);
        }
        if (AMODE == 0) {
#pragma unroll
            for (int i = 0; i < 2; ++i) {
                int c = i * 256 + tid;
                int r = c >> 2;
                long go = (rb + r) * lda + k0 + ((cs ^ (r & 3)) << 3);
                gload16(ahT + go, &Ah[c << 3]);
                gload16(alT + go, &Al[c << 3]);
            }
        } else {
            // convert fp32 -> bf16 hi/lo (HW cvt), store to swizzled LDS slot
#pragma unroll
            for (int it = 0; it < 4; ++it) {
                float xs[4] = {av[it].x, av[it].y, av[it].z, av[it].w};
                short4v hv, lv;
#pragma unroll
                for (int e = 0; e < 4; ++e) {
                    float x = xs[e] * amask[it];
                    u16 hh = f2bf(x);
                    hv[e] = (short)hh;
                    lv[e] = (short)f2bf(x - bf2f(hh));
                }
                int r = 32 * it + ar;
                int bs = ((((ac >> 3) ^ (r & 3))) << 4) | ((ac & 4) << 1);
                *(short4v*)((char*)Ah + r * 64 + bs) = hv;
                *(short4v*)((char*)Al + r * 64 + bs) = lv;
            }
        }
        __syncthreads();    // drains vmcnt(0)+lgkmcnt(0): tile ready
        // fragments + MFMA (swizzled slot addressing)
        short8 fah[4], fal[4];
#pragma unroll
        for (int i = 0; i < 4; ++i) {
            int m = wr + 16 * i + lm;
            int sl = (quad ^ (m & 3)) << 3;
            fah[i] = *(const short8*)&Ah[(m << 5) + sl];
            fal[i] = *(const short8*)&Al[(m << 5) + sl];
        }
#pragma unroll
        for (int j = 0; j < 4; ++j) {
            int n = wc + 16 * j + lm;
            int sl = (quad ^ (n & 3)) << 3;
            short8 fbh = *(const short8*)&Bh[(n << 5) + sl];
            short8 fbl = *(const short8*)&Bl[(n << 5) + sl];
#pragma unroll
            for (int i = 0; i < 4; ++i) {
                acc[i][j] = __builtin_amdgcn_mfma_f32_16x16x32_bf16(fah[i], fbh, acc[i][j], 0, 0, 0);
                acc[i][j] = __builtin_amdgcn_mfma_f32_16x16x32_bf16(fal[i], fbh, acc[i][j], 0, 0, 0);
                acc[i][j] = __builtin_amdgcn_mfma_f32_16x16x32_bf16(fah[i], fbl, acc[i][j], 0, 0, 0);
            }
        }
    }
    // epilogue
#pragma unroll
    for (int j = 0; j < 4; ++j) {
        int col = wc + 16 * j + lm;
        float bj = biasT[col];
#pragma unroll
        for (int i = 0; i < 4; ++i) {
            long rbase = rb + wr + 16 * i + quad * 4;
#pragma unroll
            for (int r = 0; r < 4; ++r) {
                float vv = acc[i][j][r] + bj;
                if (RELU) vv = fmaxf(vv, 0.f);
                long off = (rbase + r) * d.ldc + d.coff + n0 + col;
                if (OUTS == 0) {
                    ((float*)d.Ca)[off] = vv;
                } else {
                    u16 hh = f2bf(vv);
                    ((u16*)d.Ca)[off] = hh;
                    ((u16*)d.Cb)[off] = f2bf(vv - bf2f(hh));
                }
            }
        }
    }
}

// ---------------------------------------------------------------------------
// k_prep: per pair -- denom, v-pool, z-pool, assemble XF/XH (1536 each),
// written directly as bf16 hi/lo (pre-split for the head GEMMs).
// ---------------------------------------------------------------------------
__global__ __launch_bounds__(256) void k_prep(
    const int* __restrict__ pairIdx, const int* __restrict__ prb,
    const float* __restrict__ dm, const float* __restrict__ v,
    const float* __restrict__ obs,
    u16* __restrict__ XFh, u16* __restrict__ XFl,
    u16* __restrict__ XHh, u16* __restrict__ XHl)
{
    int pv = blockIdx.x, c = threadIdx.x;
    int p = pairIdx[pv];
    long xo = (long)pv * 1536;
    if (p < 0) {
        for (int s = 0; s < 6; ++s) {
            XFh[xo + s * 256 + c] = 0; XFl[xo + s * 256 + c] = 0;
            XHh[xo + s * 256 + c] = 0; XHl[xo + s * 256 + c] = 0;
        }
        return;
    }
    __shared__ float sw[22];
    if (c < 22) sw[c] = dm[p * 22 + c];
    __syncthreads();
    float denf = 0.f, denh = 0.f;
    for (int e = 1; e < 12; ++e)  denf += sw[e];
    for (int e = 12; e < 22; ++e) denh += sw[e];
    denf = 1.f / fmaxf(denf, 1.f);
    denh = 1.f / fmaxf(denh, 1.f);

    auto wsp = [&](u16* Hh, u16* Hl, long idx, float val) {
        u16 hh = f2bf(val);
        Hh[idx] = hh;
        Hl[idx] = f2bf(val - bf2f(hh));
    };

    long base = prb[pv];
    float vs = v[base * 256 + c];
    wsp(XFh, XFl, xo + c, vs);
    wsp(XHh, XHl, xo + c, vs);
    float af = 0.f, ah = 0.f;
    for (int e = 1; e < 12; ++e)  af += sw[e] * v[(base + e) * 256 + c];
    for (int e = 12; e < 22; ++e) ah += sw[e] * v[(base + e) * 256 + c];
    wsp(XFh, XFl, xo + 256 + c, af * denf);
    wsp(XHh, XHl, xo + 256 + c, ah * denh);
    const float* ob = obs + (long)p * 22 * 512;
    float w0 = sw[0];
    float z0 = ob[c] * w0;
    float z1 = ob[256 + c] * w0;
    wsp(XFh, XFl, xo + 512 + c, z0); wsp(XHh, XHl, xo + 512 + c, z0);
    wsp(XFh, XFl, xo + 768 + c, z1); wsp(XHh, XHl, xo + 768 + c, z1);
#pragma unroll
    for (int half = 0; half < 2; ++half) {
        int c2 = c + half * 256;
        float zf = 0.f, zh = 0.f;
        for (int e = 1; e < 12; ++e)  zf += sw[e] * ob[(long)e * 512 + c2];
        for (int e = 12; e < 22; ++e) zh += sw[e] * ob[(long)e * 512 + c2];
        wsp(XFh, XFl, xo + 1024 + c2, zf * denf);
        wsp(XHh, XHl, xo + 1024 + c2, zh * denh);
    }
}

// ---------------------------------------------------------------------------
// Final: L2 layer fused + logits + argmax + log-softmax + value dot; scatter.
// ---------------------------------------------------------------------------
__global__ __launch_bounds__(128) void k_final(
    const float* __restrict__ g1, const float* __restrict__ vV,
    const float* __restrict__ L2, const float* __restrict__ bL2,
    const float* __restrict__ L3, const float* __restrict__ bL3,
    const float* __restrict__ V2, const float* __restrict__ bV2,
    const int* __restrict__ pairIdx, const int* __restrict__ ps,
    float* __restrict__ out)
{
    int pv = blockIdx.x;
    int p = pairIdx[pv];
    if (p < 0) return;
    int c = threadIdx.x;
    int t = (pv >= ps[1]) + (pv >= ps[2]);

    __shared__ float sg1[256], sg2[128], sval[2];
    const float* g1p = g1 + (long)pv * 256;
    sg1[c] = g1p[c];
    sg1[c + 128] = g1p[c + 128];

    const float* vv = vV + (long)pv * 256;
    const float* v2t = V2 + t * 256;
    float s = vv[c] * v2t[c] + vv[c + 128] * v2t[c + 128];
    for (int off = 32; off; off >>= 1) s += __shfl_down(s, off);
    if ((c & 63) == 0) sval[c >> 6] = s;
    __syncthreads();

    const float* l2 = L2 + (long)t * 256 * 128 + c;
    float a = bL2[t * 128 + c];
#pragma unroll 8
    for (int k = 0; k < 256; ++k) a = fmaf(sg1[k], l2[(long)k * 128], a);
    sg2[c] = fmaxf(a, 0.f);
    __syncthreads();

    if (c < 64) {
        float lg = -3.0e38f;
        if (c < 21) {
            const float* l3t = L3 + (long)t * 128 * 21 + c;
            float acc = bL3[t * 21 + c];
            for (int k = 0; k < 128; ++k) acc = fmaf(sg2[k], l3t[k * 21], acc);
            lg = acc;
        }
        float mv = lg; int mi = (c < 21) ? c : 9999;
        for (int off = 32; off; off >>= 1) {
            float ov = __shfl_down(mv, off);
            int oi = __shfl_down(mi, off);
            if (ov > mv || (ov == mv && oi < mi)) { mv = ov; mi = oi; }
        }
        mv = __shfl(mv, 0); mi = __shfl(mi, 0);
        float e = (c < 21) ? expf(lg - mv) : 0.f;
        for (int off = 32; off; off >>= 1) e += __shfl_down(e, off);
        if (c == 0) {
            out[p] = (float)mi;
            out[NP_ + p] = sval[0] + sval[1] + bV2[t];
            out[2 * NP_ + p] = -logf(e);
        }
    }
}

// ---------------------------------------------------------------------------
extern "C" void kernel_launch(void* const* d_in, const int* in_sizes, int n_in,
                              void* d_out, int out_size, void* d_ws, size_t ws_size,
                              hipStream_t stream)
{
    const float* obs = (const float*)d_in[0];
    const int* hete = (const int*)d_in[1];
    const void* dead = d_in[2];
    const float* W1 = (const float*)d_in[3];  const float* b1 = (const float*)d_in[4];
    const float* W2 = (const float*)d_in[5];  const float* b2 = (const float*)d_in[6];
    const float* WCf = (const float*)d_in[7]; const float* bCf = (const float*)d_in[8];
    const float* WMf = (const float*)d_in[9]; const float* bMf = (const float*)d_in[10];
    const float* WCh = (const float*)d_in[11]; const float* bCh = (const float*)d_in[12];
    const float* WMh = (const float*)d_in[13]; const float* bMh = (const float*)d_in[14];
    const float* L1 = (const float*)d_in[15]; const float* bL1 = (const float*)d_in[16];
    const float* L2 = (const float*)d_in[17]; const float* bL2 = (const float*)d_in[18];
    const float* L3 = (const float*)d_in[19]; const float* bL3 = (const float*)d_in[20];
    const float* V1 = (const float*)d_in[21]; const float* bV1 = (const float*)d_in[22];
    const float* V2 = (const float*)d_in[23]; const float* bV2 = (const float*)d_in[24];
    float* out = (float*)d_out;

    // ---- workspace carve-up (identical footprint to previous version) ----
    int* wsI = (int*)d_ws;
    int* pairIdx = wsI + 16;
    int* prb = pairIdx + PV_;
    int* rowObs = prb + PV_;
    long fbase = ((16L + PV_ + PV_ + RV_) + 63) & ~63L;
    float* wsF = (float*)d_ws;
    float* dm = wsF + fbase;
    float* cur = dm + NDEAD_;
    auto allocUS = [&](long K) { u16* p = (u16*)cur; cur += (3L * 256 * K) / 2; return p; };
    u16* W1h = allocUS(512);  u16* W1l = allocUS(512);
    u16* W2h = allocUS(256);  u16* W2l = allocUS(256);
    u16* WCfh = allocUS(512); u16* WCfl = allocUS(512);
    u16* WChh = allocUS(512); u16* WChl = allocUS(512);
    u16* WMfh = allocUS(1536); u16* WMfl = allocUS(1536);
    u16* WMhh = allocUS(1536); u16* WMhl = allocUS(1536);
    u16* L1h = allocUS(512);  u16* L1l = allocUS(512);
    u16* V1h = allocUS(512);  u16* V1l = allocUS(512);
    float* regA = cur;                               // RV_*256 floats
    float* regB = regA + (long)RV_ * 256;            // RV_*256 floats

    // regA overlays: h1 (hi/lo) for P1 phase, then XF/XH (hi/lo) for heads
    u16* h1h = (u16*)regA;
    u16* h1l = h1h + (long)RV_ * 256;                // ends exactly at regB
    u16* XFh = (u16*)regA;
    u16* XFl = XFh + (long)PV_ * 1536;
    u16* XHh = XFl + (long)PV_ * 1536;
    u16* XHl = XHh + (long)PV_ * 1536;
    // regB overlays: v fp32, then vC/vM (hi/lo) + g1/vV fp32
    float* v = regB;
    u16* vCh = (u16*)regB;
    u16* vCl = vCh + (long)PV_ * 512;
    u16* vMh = vCl + (long)PV_ * 512;
    u16* vMl = vMh + (long)PV_ * 512;
    float* g1 = (float*)(vMl + (long)PV_ * 512);
    float* vV = g1 + (long)PV_ * 256;

    // ---- bookkeeping ----
    k_bucket<<<1, 256, 0, stream>>>((const unsigned*)dead, hete, wsI);
    k_deadmask<<<264, 256, 0, stream>>>(dead, wsI, dm);
    k_rowobs<<<266, 256, 0, stream>>>(wsI + 1, wsI + 4, wsI + 8, pairIdx, dm, rowObs);

    // ---- weight conversion: single fused launch ----
    {
        WCA wa;
        const float* Ws[8] = {W1, W2, WCf, WCh, WMf, WMh, L1, V1};
        u16* His[8] = {W1h, W2h, WCfh, WChh, WMfh, WMhh, L1h, V1h};
        u16* Los[8] = {W1l, W2l, WCfl, WChl, WMfl, WMhl, L1l, V1l};
        int Ks[8] = {512, 256, 512, 512, 1536, 1536, 512, 512};
        int acc_b = 0; wa.bs[0] = 0;
        for (int i = 0; i < 8; ++i) {
            wa.W[i] = Ws[i]; wa.Hi[i] = His[i]; wa.Lo[i] = Los[i]; wa.K[i] = Ks[i];
            acc_b += 3 * Ks[i] / 8; wa.bs[i + 1] = acc_b;
        }
        k_wconv<<<acc_b, 256, 0, stream>>>(wa);
    }

    GA4 g;
    auto setd = [&](int i, const void* Aa, const void* Ab, const u16* Bh_, const u16* Bl_,
                    const float* bias, void* Ca, void* Cb, long lda_, long ldc_, int K_, int coff_) {
        g.d[i] = GD{Aa, Ab, Bh_, Bl_, bias, Ca, Cb, lda_, ldc_, K_, coff_};
    };

    // ---- phase 1a: h1 = relu(obs@W1+b1), output pre-split hi/lo ----
    for (int i = 0; i < 4; ++i)
        setd(i, obs, nullptr, W1h, W1l, b1, h1h, h1l, 512, 256, 512, 0);
    k_mgemm<1, true, 1><<<dim3(RV_ / 128, 2, 1), 256, 0, stream>>>(g, rowObs, wsI + 9);

    // ---- phase 1b: v = h1@W2+b2 (pure bf16, gload_lds both sides) ----
    for (int i = 0; i < 4; ++i)
        setd(i, h1h, h1l, W2h, W2l, b2, v, nullptr, 256, 256, 256, 0);
    k_mgemm<0, false, 0><<<dim3(RV_ / 128, 2, 1), 256, 0, stream>>>(g, nullptr, wsI + 9);

    // ---- pair prep (writes XF/XH pre-split) ----
    k_prep<<<PV_, 256, 0, stream>>>(pairIdx, prb, dm, v, obs, XFh, XFl, XHh, XHl);

    // ---- heads H1+H2 fused into one z=4 launch (216 blocks) ----
    setd(0, XFh, XFl, WCfh, WCfl, bCf, vCh, vCl, 1536, 512, 512, 0);
    setd(1, XHh, XHl, WChh, WChl, bCh, vCh, vCl, 1536, 512, 512, 256);
    setd(2, XFh, XFl, WMfh, WMfl, bMf, vMh, vMl, 1536, 512, 1536, 0);
    setd(3, XHh, XHl, WMhh, WMhl, bMh, vMh, vMl, 1536, 512, 1536, 256);
    k_mgemm<0, true, 1><<<dim3(PV_ / 128, 2, 4), 256, 0, stream>>>(g, nullptr, wsI + 5);

    // ---- H3: g1 = relu(vC@L1); vV = relu(vM@V1) ----
    setd(0, vCh, vCl, L1h, L1l, bL1, g1, nullptr, 512, 256, 512, 0);
    setd(1, vMh, vMl, V1h, V1l, bV1, vV, nullptr, 512, 256, 512, 0);
    setd(2, vCh, vCl, L1h, L1l, bL1, g1, nullptr, 512, 256, 512, 0);
    setd(3, vCh, vCl, L1h, L1l, bL1, g1, nullptr, 512, 256, 512, 0);
    k_mgemm<0, true, 0><<<dim3(PV_ / 128, 2, 2), 256, 0, stream>>>(g, nullptr, wsI + 5);

    k_final<<<PV_, 128, 0, stream>>>(g1, vV, L2, bL2, L3, bL3, V2, bV2,
                                     pairIdx, wsI + 4, out);
    (void)in_sizes; (void)n_in; (void)out_size; (void)ws_size;
}

// Round 2
// 520.279 us; speedup vs baseline: 1.1871x; 1.0864x over previous
//
#include <hip/hip_runtime.h>
#include <cstdint>

// Problem constants
#define T_ 64
#define A_ 48
#define NP_ 3072      // T*A pairs
#define E_ 22
#define RAW_ 512
#define H_ 256
#define NACT_ 21
#define NTP_ 3
#define PV_ 3456      // padded virtual pair rows (27 tiles of 128)
#define RV_ 68096     // padded virtual entity rows (532 tiles of 128)
#define NDEAD_ 67584  // NP_*E_

typedef unsigned short u16;
typedef __attribute__((ext_vector_type(8))) short short8;
typedef __attribute__((ext_vector_type(4))) short short4v;
typedef __attribute__((ext_vector_type(4))) float floatx4;

// HW RNE f32->bf16 via v_cvt_pk_bf16_f32. Self-pair form is operand-order-proof.
__device__ __forceinline__ u16 f2bf(float x) {
    unsigned r;
    asm("v_cvt_pk_bf16_f32 %0, %1, %1" : "=v"(r) : "v"(x));
    return (u16)r;
}
__device__ __forceinline__ float bf2f(u16 h) {
    return __uint_as_float(((unsigned)h) << 16);
}

// global -> LDS direct DMA, 16B per lane. LDS dest linear (uniform + lane*16);
// global src per-lane (carries the swizzle).
typedef __attribute__((address_space(1))) const void* gp_t;
typedef __attribute__((address_space(3))) void* lp_t;
__device__ __forceinline__ void gload16(const void* g, void* l) {
    __builtin_amdgcn_global_load_lds((gp_t)g, (lp_t)l, 16, 0, 0);
}

// raw barrier with explicit drain (T3-min recipe). memory clobber pins VMEM/DS
// issue order; sched_barrier(0) stops next-tile ds_reads hoisting above.
__device__ __forceinline__ void sync_tile() {
    asm volatile("s_waitcnt vmcnt(0) lgkmcnt(0)" ::: "memory");
    __builtin_amdgcn_s_barrier();
    __builtin_amdgcn_sched_barrier(0);
}

// 16B-slot swizzle key per row: rows r, r+2 must land in different slots too
// (row stride 64B == half the 128B bank period) -> key = ((r>>1)^r)&3.
__device__ __forceinline__ int swzk(int r) { return ((r >> 1) ^ r) & 3; }

// ---------------------------------------------------------------------------
// K_bucket: sniff dead dtype, count pairs per type, build bucketed pair list.
// wsI layout: [0]=mode, [1..3]=cnt, [4..6]=ps, [8..10]=rs,
//             [16..16+PV)=pairIdx, then prb[PV]
// ---------------------------------------------------------------------------
__global__ void k_bucket(const unsigned* __restrict__ deadRaw,
                         const int* __restrict__ hete, int* __restrict__ wsI)
{
    __shared__ int fl[2];
    __shared__ int sc[3], cur[3], sps[3], srs[3];
    int tid = threadIdx.x;
    if (tid < 2) fl[tid] = 0;
    if (tid < 3) { sc[tid] = 0; cur[tid] = 0; }
    __syncthreads();
    int ni = 0, nf = 0;
    for (int i = tid; i < 1024; i += 256) {
        unsigned w = deadRaw[i];
        if (w > 1u) ni = 1;
        if (w != 0u && w != 0x3F800000u) nf = 1;
    }
    if (ni) atomicOr(&fl[0], 1);
    if (nf) atomicOr(&fl[1], 1);
    for (int p = tid; p < NP_; p += 256) atomicAdd(&sc[hete[p]], 1);
    __syncthreads();
    if (tid == 0) {
        int c0 = sc[0], c1 = sc[1], c2 = sc[2];
        int p1 = (c0 + 127) & ~127;
        int p2 = p1 + ((c1 + 127) & ~127);
        sps[0] = 0; sps[1] = p1; sps[2] = p2;
        int r1 = (22 * c0 + 127) & ~127;
        int r2 = r1 + ((22 * c1 + 127) & ~127);
        srs[0] = 0; srs[1] = r1; srs[2] = r2;
        wsI[0] = fl[0] ? (fl[1] ? 2 : 1) : 0;  // 0=int32,1=float32,2=byte
        wsI[1] = c0; wsI[2] = c1; wsI[3] = c2;
        wsI[4] = 0; wsI[5] = p1; wsI[6] = p2;
        wsI[8] = 0; wsI[9] = r1; wsI[10] = r2;
    }
    __syncthreads();
    int* pairIdx = wsI + 16;
    int* prb = pairIdx + PV_;
    for (int pv = tid; pv < PV_; pv += 256) pairIdx[pv] = -1;
    __syncthreads();
    for (int p = tid; p < NP_; p += 256) {
        int t = hete[p];
        int pos = atomicAdd(&cur[t], 1);
        pairIdx[sps[t] + pos] = p;
    }
    for (int pv = tid; pv < PV_; pv += 256) {
        int t = (pv >= sps[1]) + (pv >= sps[2]);
        prb[pv] = srs[t] + 22 * (pv - sps[t]);
    }
}

__global__ void k_deadmask(const void* __restrict__ dead,
                           const int* __restrict__ wsI, float* __restrict__ dm)
{
    int i = blockIdx.x * 256 + threadIdx.x;
    if (i >= NDEAD_) return;
    int mode = wsI[0];
    bool d;
    if (mode == 0)      d = ((const int*)dead)[i] != 0;
    else if (mode == 1) d = ((const float*)dead)[i] != 0.f;
    else                d = ((const unsigned char*)dead)[i] != 0;
    dm[i] = d ? 0.f : 1.f;
}

// rowObs[rv] = obs row index for virtual row, or -1 (padding OR dead -> zero A row)
__global__ void k_rowobs(const int* __restrict__ cnt, const int* __restrict__ ps,
                         const int* __restrict__ rs, const int* __restrict__ pairIdx,
                         const float* __restrict__ dm, int* __restrict__ rowObs)
{
    int rv = blockIdx.x * 256 + threadIdx.x;
    if (rv >= RV_) return;
    int t = (rv >= rs[1]) + (rv >= rs[2]);
    int local = rv - rs[t];
    int out = -1;
    if (local < 22 * cnt[t]) {
        int pl = local / 22;
        int e = local - pl * 22;
        int p = pairIdx[ps[t] + pl];
        if (p >= 0) {
            int oi = p * 22 + e;
            if (dm[oi] != 0.f) out = oi;
        }
    }
    rowObs[rv] = out;
}

// ---------------------------------------------------------------------------
// k_wconv (fused, all 8 weight matrices): W[t][k][n] fp32 -> hi/lo bf16 [t][n][k]
// ---------------------------------------------------------------------------
struct WCA {
    const float* W[8]; u16* Hi[8]; u16* Lo[8]; int K[8]; int bs[9];
};
__global__ __launch_bounds__(256) void k_wconv(WCA a)
{
    int blk = blockIdx.x;
    int s = 0;
#pragma unroll
    for (int i = 1; i < 8; ++i) if (blk >= a.bs[i]) s = i;
    int lb = blk - a.bs[s];
    int K = a.K[s];
    int K8 = K >> 3;
    int kc = lb % K8;
    int t  = lb / K8;
    int n  = threadIdx.x;
    const float* w = a.W[s] + (long)t * K * 256 + n;
    short8 hv, lv;
#pragma unroll
    for (int j = 0; j < 8; ++j) {
        float x = w[(long)(kc * 8 + j) * 256];
        u16 hh = f2bf(x);
        hv[j] = (short)hh;
        lv[j] = (short)f2bf(x - bf2f(hh));
    }
    long o = ((long)t * 256 + n) * K + kc * 8;
    *(short8*)(a.Hi[s] + o) = hv;
    *(short8*)(a.Lo[s] + o) = lv;
}

// ---------------------------------------------------------------------------
// MFMA GEMM, bf16x3 split: C = op(A) @ B[type] + bias[type], optional relu.
// Tile 128x128, BK=32, 256 threads. Double-buffered LDS (64KB), T3-min
// 2-phase pipeline: prefetch tile t+1 (global_load_lds / reg loads) BEFORE
// computing tile t; one raw s_barrier + vmcnt(0) drain per K-step, so DMA
// latency hides under ds_read+MFMA.
// AMODE 0: A pre-split bf16 hi/lo via gload_lds. AMODE 1: A fp32 row-gather,
// reg-staged, HW cvt split placed AFTER the MFMA cluster (issue-early/
// write-late, T14).
// OUTS 0: fp32 C direct. OUTS 1: C hi/lo bf16, staged through LDS for
// fully-coalesced 16B stores (fixes 2B-store write amplification).
// Swizzle (both-sides, rule #21): slot' = slot ^ swzk(row) on global source,
// conv write, and frag read.
// ---------------------------------------------------------------------------
struct GD {
    const void* Aa; const void* Ab;   // AMODE0: hi,lo u16; AMODE1: fp32, unused
    const u16* Bh; const u16* Bl;
    const float* bias;
    void* Ca; void* Cb;               // OUTS0: fp32, unused; OUTS1: hi,lo u16
    long lda; long ldc;
    int K; int coff;
};
struct GA4 { GD d[4]; };

template<int AMODE, bool RELU, int OUTS>
__global__ __launch_bounds__(256) void k_mgemm(
    GA4 ga, const int* __restrict__ rowIdx, const int* __restrict__ starts)
{
    // 64KB: buffer b at smem + b*16384: Ah +0, Al +4096, Bh +8192, Bl +12288
    __shared__ short smem[32768];
    const int tid = threadIdx.x;
    const GD d = ga.d[blockIdx.z];
    const long rb = (long)blockIdx.x * 128;
    const int n0 = blockIdx.y * 128;
    const int t = (rb >= starts[0]) + (rb >= starts[1]);
    const int K = d.K;
    const long lda = d.lda;
    const u16* bhT = d.Bh + ((long)t * 256 + n0) * K;
    const u16* blT = d.Bl + ((long)t * 256 + n0) * K;
    const float* biasT = d.bias + (long)t * 256 + n0;

    const int cs = tid & 3;             // 16B slot within 64B row

    // AMODE1 reg-stage mapping: 4 iters of 32 rows x 32 k
    const int ar = tid >> 3;            // 0..31
    const int ac = (tid & 7) * 4;       // 0..28
    long arow[4]; float amask[4];
    const float* Afp = (const float*)d.Aa;
    if (AMODE == 1) {
#pragma unroll
        for (int it = 0; it < 4; ++it) {
            int r = 32 * it + ar;
            int i0 = rowIdx[rb + r];
            amask[it] = (i0 < 0) ? 0.f : 1.f;
            arow[it] = (i0 < 0) ? 0 : (long)i0 * lda;
        }
    }
    const u16* ahT = (const u16*)d.Aa;
    const u16* alT = (const u16*)d.Ab;

    // wave tiling
    const int wave = tid >> 6;
    const int lane = tid & 63;
    const int wr = (wave >> 1) * 64;
    const int wc = (wave & 1) * 64;
    const int lm = lane & 15;
    const int quad = lane >> 4;

    auto stageB = [&](int b, int k0) {
        short* Bh = smem + b * 16384 + 8192;
        short* Bl = smem + b * 16384 + 12288;
#pragma unroll
        for (int i = 0; i < 2; ++i) {
            int c = i * 256 + tid;
            int r = c >> 2;
            long go = (long)r * K + k0 + ((cs ^ swzk(r)) << 3);
            gload16(bhT + go, &Bh[c << 3]);
            gload16(blT + go, &Bl[c << 3]);
        }
    };
    auto stageA0 = [&](int b, int k0) {
        short* Ah = smem + b * 16384;
        short* Al = smem + b * 16384 + 4096;
#pragma unroll
        for (int i = 0; i < 2; ++i) {
            int c = i * 256 + tid;
            int r = c >> 2;
            long go = (rb + r) * lda + k0 + ((cs ^ swzk(r)) << 3);
            gload16(ahT + go, &Ah[c << 3]);
            gload16(alT + go, &Al[c << 3]);
        }
    };
    auto convertA = [&](int b, const float4* av) {
        short* AhW = smem + b * 16384;
        short* AlW = AhW + 4096;
#pragma unroll
        for (int it = 0; it < 4; ++it) {
            float xs[4] = {av[it].x, av[it].y, av[it].z, av[it].w};
            short4v hv, lv;
#pragma unroll
            for (int e = 0; e < 4; ++e) {
                float x = xs[e] * amask[it];
                u16 hh = f2bf(x);
                hv[e] = (short)hh;
                lv[e] = (short)f2bf(x - bf2f(hh));
            }
            int r = 32 * it + ar;
            int bs = (((ac >> 3) ^ swzk(r)) << 4) | ((ac & 4) << 1);
            *(short4v*)((char*)AhW + r * 64 + bs) = hv;
            *(short4v*)((char*)AlW + r * 64 + bs) = lv;
        }
    };

    floatx4 acc[4][4];
#pragma unroll
    for (int i = 0; i < 4; ++i)
#pragma unroll
        for (int j = 0; j < 4; ++j) acc[i][j] = (floatx4){0.f, 0.f, 0.f, 0.f};

    // ---- prologue: stage tile 0 into buffer 0 ----
    if (AMODE == 1) {
        float4 av0[4];
#pragma unroll
        for (int it = 0; it < 4; ++it)
            av0[it] = *(const float4*)(Afp + arow[it] + ac);
        stageB(0, 0);        // DMA overlaps the conversion below
        convertA(0, av0);
    } else {
        stageA0(0, 0);
        stageB(0, 0);
    }
    sync_tile();

    const int nt = K >> 5;
    int cur = 0;
    for (int ti = 0; ti < nt; ++ti) {
        const bool pf = (ti + 1) < nt;
        const int k1 = (ti + 1) << 5;
        float4 av2[4];
        if (pf) {
            if (AMODE == 1) {
#pragma unroll
                for (int it = 0; it < 4; ++it)
                    av2[it] = *(const float4*)(Afp + arow[it] + k1 + ac);
            } else {
                stageA0(cur ^ 1, k1);
            }
            stageB(cur ^ 1, k1);
        }
        // compute tile ti from buffer cur
        const short* Ah = smem + cur * 16384;
        const short* Al = Ah + 4096;
        const short* Bh = Ah + 8192;
        const short* Bl = Ah + 12288;
        short8 fah[4], fal[4];
#pragma unroll
        for (int i = 0; i < 4; ++i) {
            int m = wr + 16 * i + lm;
            int sl = (quad ^ swzk(m)) << 3;
            fah[i] = *(const short8*)&Ah[(m << 5) + sl];
            fal[i] = *(const short8*)&Al[(m << 5) + sl];
        }
#pragma unroll
        for (int j = 0; j < 4; ++j) {
            int n = wc + 16 * j + lm;
            int sl = (quad ^ swzk(n)) << 3;
            short8 fbh = *(const short8*)&Bh[(n << 5) + sl];
            short8 fbl = *(const short8*)&Bl[(n << 5) + sl];
#pragma unroll
            for (int i = 0; i < 4; ++i) {
                acc[i][j] = __builtin_amdgcn_mfma_f32_16x16x32_bf16(fah[i], fbh, acc[i][j], 0, 0, 0);
                acc[i][j] = __builtin_amdgcn_mfma_f32_16x16x32_bf16(fal[i], fbh, acc[i][j], 0, 0, 0);
                acc[i][j] = __builtin_amdgcn_mfma_f32_16x16x32_bf16(fah[i], fbl, acc[i][j], 0, 0, 0);
            }
        }
        // A conversion for tile ti+1 AFTER the MFMA cluster: its global loads
        // (issued at loop top) land under the compute phase.
        if (pf && AMODE == 1) convertA(cur ^ 1, av2);
        sync_tile();
        cur ^= 1;
    }

    // ---- epilogue ----
    if (OUTS == 0) {
        float* C = (float*)d.Ca;
#pragma unroll
        for (int j = 0; j < 4; ++j) {
            int col = wc + 16 * j + lm;
            float bj = biasT[col];
#pragma unroll
            for (int i = 0; i < 4; ++i) {
                long rbase = rb + wr + 16 * i + quad * 4;
#pragma unroll
                for (int r = 0; r < 4; ++r) {
                    float vv = acc[i][j][r] + bj;
                    if (RELU) vv = fmaxf(vv, 0.f);
                    C[(rbase + r) * d.ldc + d.coff + n0 + col] = vv;
                }
            }
        }
    } else {
        // stage hi/lo C-tile through LDS (reuse 64KB), then 16B coalesced
        // stores. Col swizzle key (row>>2)&3 spreads the 4 quad-rows across
        // distinct 32B bank spans (writes 2-way = free; reads conflict-free).
        u16* Chi = (u16*)smem;            // 128x128 u16 = 32KB
        u16* Clo = Chi + 16384;
#pragma unroll
        for (int j = 0; j < 4; ++j) {
            int col = wc + 16 * j + lm;
            float bj = biasT[col];
#pragma unroll
            for (int i = 0; i < 4; ++i) {
                int row0 = wr + 16 * i + quad * 4;
#pragma unroll
                for (int r = 0; r < 4; ++r) {
                    float vv = acc[i][j][r] + bj;
                    if (RELU) vv = fmaxf(vv, 0.f);
                    int row = row0 + r;
                    int cc = col ^ (((row >> 2) & 3) << 4);
                    u16 hh = f2bf(vv);
                    Chi[row * 128 + cc] = hh;
                    Clo[row * 128 + cc] = f2bf(vv - bf2f(hh));
                }
            }
        }
        asm volatile("s_waitcnt lgkmcnt(0)" ::: "memory");
        __builtin_amdgcn_s_barrier();
        __builtin_amdgcn_sched_barrier(0);
        u16* Ca = (u16*)d.Ca;
        u16* Cb = (u16*)d.Cb;
#pragma unroll
        for (int s = 0; s < 8; ++s) {
            int ch = s * 256 + tid;
            int row = ch >> 4;
            int gcol = (ch & 15) * 8;
            int lo = row * 128 + (gcol ^ (((row >> 2) & 3) << 4));
            short8 hv = *(const short8*)&Chi[lo];
            short8 lv = *(const short8*)&Clo[lo];
            long go = (rb + row) * d.ldc + d.coff + n0 + gcol;
            *(short8*)(Ca + go) = hv;
            *(short8*)(Cb + go) = lv;
        }
    }
}

// ---------------------------------------------------------------------------
// k_prep: per pair -- denom, v-pool, z-pool, assemble XF/XH (1536 each),
// written directly as bf16 hi/lo (pre-split for the head GEMMs).
// ---------------------------------------------------------------------------
__global__ __launch_bounds__(256) void k_prep(
    const int* __restrict__ pairIdx, const int* __restrict__ prb,
    const float* __restrict__ dm, const float* __restrict__ v,
    const float* __restrict__ obs,
    u16* __restrict__ XFh, u16* __restrict__ XFl,
    u16* __restrict__ XHh, u16* __restrict__ XHl)
{
    int pv = blockIdx.x, c = threadIdx.x;
    int p = pairIdx[pv];
    long xo = (long)pv * 1536;
    if (p < 0) {
        for (int s = 0; s < 6; ++s) {
            XFh[xo + s * 256 + c] = 0; XFl[xo + s * 256 + c] = 0;
            XHh[xo + s * 256 + c] = 0; XHl[xo + s * 256 + c] = 0;
        }
        return;
    }
    __shared__ float sw[22];
    if (c < 22) sw[c] = dm[p * 22 + c];
    __syncthreads();
    float denf = 0.f, denh = 0.f;
    for (int e = 1; e < 12; ++e)  denf += sw[e];
    for (int e = 12; e < 22; ++e) denh += sw[e];
    denf = 1.f / fmaxf(denf, 1.f);
    denh = 1.f / fmaxf(denh, 1.f);

    auto wsp = [&](u16* Hh, u16* Hl, long idx, float val) {
        u16 hh = f2bf(val);
        Hh[idx] = hh;
        Hl[idx] = f2bf(val - bf2f(hh));
    };

    long base = prb[pv];
    float vs = v[base * 256 + c];
    wsp(XFh, XFl, xo + c, vs);
    wsp(XHh, XHl, xo + c, vs);
    float af = 0.f, ah = 0.f;
    for (int e = 1; e < 12; ++e)  af += sw[e] * v[(base + e) * 256 + c];
    for (int e = 12; e < 22; ++e) ah += sw[e] * v[(base + e) * 256 + c];
    wsp(XFh, XFl, xo + 256 + c, af * denf);
    wsp(XHh, XHl, xo + 256 + c, ah * denh);
    const float* ob = obs + (long)p * 22 * 512;
    float w0 = sw[0];
    float z0 = ob[c] * w0;
    float z1 = ob[256 + c] * w0;
    wsp(XFh, XFl, xo + 512 + c, z0); wsp(XHh, XHl, xo + 512 + c, z0);
    wsp(XFh, XFl, xo + 768 + c, z1); wsp(XHh, XHl, xo + 768 + c, z1);
#pragma unroll
    for (int half = 0; half < 2; ++half) {
        int c2 = c + half * 256;
        float zf = 0.f, zh = 0.f;
        for (int e = 1; e < 12; ++e)  zf += sw[e] * ob[(long)e * 512 + c2];
        for (int e = 12; e < 22; ++e) zh += sw[e] * ob[(long)e * 512 + c2];
        wsp(XFh, XFl, xo + 1024 + c2, zf * denf);
        wsp(XHh, XHl, xo + 1024 + c2, zh * denh);
    }
}

// ---------------------------------------------------------------------------
// Final: L2 layer fused + logits + argmax + log-softmax + value dot; scatter.
// ---------------------------------------------------------------------------
__global__ __launch_bounds__(128) void k_final(
    const float* __restrict__ g1, const float* __restrict__ vV,
    const float* __restrict__ L2, const float* __restrict__ bL2,
    const float* __restrict__ L3, const float* __restrict__ bL3,
    const float* __restrict__ V2, const float* __restrict__ bV2,
    const int* __restrict__ pairIdx, const int* __restrict__ ps,
    float* __restrict__ out)
{
    int pv = blockIdx.x;
    int p = pairIdx[pv];
    if (p < 0) return;
    int c = threadIdx.x;
    int t = (pv >= ps[1]) + (pv >= ps[2]);

    __shared__ float sg1[256], sg2[128], sval[2];
    const float* g1p = g1 + (long)pv * 256;
    sg1[c] = g1p[c];
    sg1[c + 128] = g1p[c + 128];

    const float* vv = vV + (long)pv * 256;
    const float* v2t = V2 + t * 256;
    float s = vv[c] * v2t[c] + vv[c + 128] * v2t[c + 128];
    for (int off = 32; off; off >>= 1) s += __shfl_down(s, off);
    if ((c & 63) == 0) sval[c >> 6] = s;
    __syncthreads();

    const float* l2 = L2 + (long)t * 256 * 128 + c;
    float a = bL2[t * 128 + c];
#pragma unroll 8
    for (int k = 0; k < 256; ++k) a = fmaf(sg1[k], l2[(long)k * 128], a);
    sg2[c] = fmaxf(a, 0.f);
    __syncthreads();

    if (c < 64) {
        float lg = -3.0e38f;
        if (c < 21) {
            const float* l3t = L3 + (long)t * 128 * 21 + c;
            float acc = bL3[t * 21 + c];
            for (int k = 0; k < 128; ++k) acc = fmaf(sg2[k], l3t[k * 21], acc);
            lg = acc;
        }
        float mv = lg; int mi = (c < 21) ? c : 9999;
        for (int off = 32; off; off >>= 1) {
            float ov = __shfl_down(mv, off);
            int oi = __shfl_down(mi, off);
            if (ov > mv || (ov == mv && oi < mi)) { mv = ov; mi = oi; }
        }
        mv = __shfl(mv, 0); mi = __shfl(mi, 0);
        float e = (c < 21) ? expf(lg - mv) : 0.f;
        for (int off = 32; off; off >>= 1) e += __shfl_down(e, off);
        if (c == 0) {
            out[p] = (float)mi;
            out[NP_ + p] = sval[0] + sval[1] + bV2[t];
            out[2 * NP_ + p] = -logf(e);
        }
    }
}

// ---------------------------------------------------------------------------
extern "C" void kernel_launch(void* const* d_in, const int* in_sizes, int n_in,
                              void* d_out, int out_size, void* d_ws, size_t ws_size,
                              hipStream_t stream)
{
    const float* obs = (const float*)d_in[0];
    const int* hete = (const int*)d_in[1];
    const void* dead = d_in[2];
    const float* W1 = (const float*)d_in[3];  const float* b1 = (const float*)d_in[4];
    const float* W2 = (const float*)d_in[5];  const float* b2 = (const float*)d_in[6];
    const float* WCf = (const float*)d_in[7]; const float* bCf = (const float*)d_in[8];
    const float* WMf = (const float*)d_in[9]; const float* bMf = (const float*)d_in[10];
    const float* WCh = (const float*)d_in[11]; const float* bCh = (const float*)d_in[12];
    const float* WMh = (const float*)d_in[13]; const float* bMh = (const float*)d_in[14];
    const float* L1 = (const float*)d_in[15]; const float* bL1 = (const float*)d_in[16];
    const float* L2 = (const float*)d_in[17]; const float* bL2 = (const float*)d_in[18];
    const float* L3 = (const float*)d_in[19]; const float* bL3 = (const float*)d_in[20];
    const float* V1 = (const float*)d_in[21]; const float* bV1 = (const float*)d_in[22];
    const float* V2 = (const float*)d_in[23]; const float* bV2 = (const float*)d_in[24];
    float* out = (float*)d_out;

    // ---- workspace carve-up (identical footprint to previous version) ----
    int* wsI = (int*)d_ws;
    int* pairIdx = wsI + 16;
    int* prb = pairIdx + PV_;
    int* rowObs = prb + PV_;
    long fbase = ((16L + PV_ + PV_ + RV_) + 63) & ~63L;
    float* wsF = (float*)d_ws;
    float* dm = wsF + fbase;
    float* cur = dm + NDEAD_;
    auto allocUS = [&](long K) { u16* p = (u16*)cur; cur += (3L * 256 * K) / 2; return p; };
    u16* W1h = allocUS(512);  u16* W1l = allocUS(512);
    u16* W2h = allocUS(256);  u16* W2l = allocUS(256);
    u16* WCfh = allocUS(512); u16* WCfl = allocUS(512);
    u16* WChh = allocUS(512); u16* WChl = allocUS(512);
    u16* WMfh = allocUS(1536); u16* WMfl = allocUS(1536);
    u16* WMhh = allocUS(1536); u16* WMhl = allocUS(1536);
    u16* L1h = allocUS(512);  u16* L1l = allocUS(512);
    u16* V1h = allocUS(512);  u16* V1l = allocUS(512);
    float* regA = cur;                               // RV_*256 floats
    float* regB = regA + (long)RV_ * 256;            // RV_*256 floats

    // regA overlays: h1 (hi/lo) for P1 phase, then XF/XH (hi/lo) for heads
    u16* h1h = (u16*)regA;
    u16* h1l = h1h + (long)RV_ * 256;                // ends exactly at regB
    u16* XFh = (u16*)regA;
    u16* XFl = XFh + (long)PV_ * 1536;
    u16* XHh = XFl + (long)PV_ * 1536;
    u16* XHl = XHh + (long)PV_ * 1536;
    // regB overlays: v fp32, then vC/vM (hi/lo) + g1/vV fp32
    float* v = regB;
    u16* vCh = (u16*)regB;
    u16* vCl = vCh + (long)PV_ * 512;
    u16* vMh = vCl + (long)PV_ * 512;
    u16* vMl = vMh + (long)PV_ * 512;
    float* g1 = (float*)(vMl + (long)PV_ * 512);
    float* vV = g1 + (long)PV_ * 256;

    // ---- bookkeeping ----
    k_bucket<<<1, 256, 0, stream>>>((const unsigned*)dead, hete, wsI);
    k_deadmask<<<264, 256, 0, stream>>>(dead, wsI, dm);
    k_rowobs<<<266, 256, 0, stream>>>(wsI + 1, wsI + 4, wsI + 8, pairIdx, dm, rowObs);

    // ---- weight conversion: single fused launch ----
    {
        WCA wa;
        const float* Ws[8] = {W1, W2, WCf, WCh, WMf, WMh, L1, V1};
        u16* His[8] = {W1h, W2h, WCfh, WChh, WMfh, WMhh, L1h, V1h};
        u16* Los[8] = {W1l, W2l, WCfl, WChl, WMfl, WMhl, L1l, V1l};
        int Ks[8] = {512, 256, 512, 512, 1536, 1536, 512, 512};
        int acc_b = 0; wa.bs[0] = 0;
        for (int i = 0; i < 8; ++i) {
            wa.W[i] = Ws[i]; wa.Hi[i] = His[i]; wa.Lo[i] = Los[i]; wa.K[i] = Ks[i];
            acc_b += 3 * Ks[i] / 8; wa.bs[i + 1] = acc_b;
        }
        k_wconv<<<acc_b, 256, 0, stream>>>(wa);
    }

    GA4 g;
    auto setd = [&](int i, const void* Aa, const void* Ab, const u16* Bh_, const u16* Bl_,
                    const float* bias, void* Ca, void* Cb, long lda_, long ldc_, int K_, int coff_) {
        g.d[i] = GD{Aa, Ab, Bh_, Bl_, bias, Ca, Cb, lda_, ldc_, K_, coff_};
    };

    // ---- phase 1a: h1 = relu(obs@W1+b1), output pre-split hi/lo ----
    for (int i = 0; i < 4; ++i)
        setd(i, obs, nullptr, W1h, W1l, b1, h1h, h1l, 512, 256, 512, 0);
    k_mgemm<1, true, 1><<<dim3(RV_ / 128, 2, 1), 256, 0, stream>>>(g, rowObs, wsI + 9);

    // ---- phase 1b: v = h1@W2+b2 (pure bf16, gload_lds both sides) ----
    for (int i = 0; i < 4; ++i)
        setd(i, h1h, h1l, W2h, W2l, b2, v, nullptr, 256, 256, 256, 0);
    k_mgemm<0, false, 0><<<dim3(RV_ / 128, 2, 1), 256, 0, stream>>>(g, nullptr, wsI + 9);

    // ---- pair prep (writes XF/XH pre-split) ----
    k_prep<<<PV_, 256, 0, stream>>>(pairIdx, prb, dm, v, obs, XFh, XFl, XHh, XHl);

    // ---- heads H1+H2 fused into one z=4 launch (216 blocks) ----
    setd(0, XFh, XFl, WCfh, WCfl, bCf, vCh, vCl, 1536, 512, 512, 0);
    setd(1, XHh, XHl, WChh, WChl, bCh, vCh, vCl, 1536, 512, 512, 256);
    setd(2, XFh, XFl, WMfh, WMfl, bMf, vMh, vMl, 1536, 512, 1536, 0);
    setd(3, XHh, XHl, WMhh, WMhl, bMh, vMh, vMl, 1536, 512, 1536, 256);
    k_mgemm<0, true, 1><<<dim3(PV_ / 128, 2, 4), 256, 0, stream>>>(g, nullptr, wsI + 5);

    // ---- H3: g1 = relu(vC@L1); vV = relu(vM@V1) ----
    setd(0, vCh, vCl, L1h, L1l, bL1, g1, nullptr, 512, 256, 512, 0);
    setd(1, vMh, vMl, V1h, V1l, bV1, vV, nullptr, 512, 256, 512, 0);
    setd(2, vCh, vCl, L1h, L1l, bL1, g1, nullptr, 512, 256, 512, 0);
    setd(3, vCh, vCl, L1h, L1l, bL1, g1, nullptr, 512, 256, 512, 0);
    k_mgemm<0, true, 0><<<dim3(PV_ / 128, 2, 2), 256, 0, stream>>>(g, nullptr, wsI + 5);

    k_final<<<PV_, 128, 0, stream>>>(g1, vV, L2, bL2, L3, bL3, V2, bV2,
                                     pairIdx, wsI + 4, out);
    (void)in_sizes; (void)n_in; (void)out_size; (void)ws_size;
}

// Round 4
// 505.737 us; speedup vs baseline: 1.2212x; 1.0288x over previous
//
#include <hip/hip_runtime.h>
#include <cstdint>

// Problem constants
#define T_ 64
#define A_ 48
#define NP_ 3072      // T*A pairs
#define E_ 22
#define RAW_ 512
#define H_ 256
#define NACT_ 21
#define NTP_ 3
#define PV_ 3456      // padded virtual pair rows (27 tiles of 128)
#define RV_ 68096     // padded virtual entity rows (532 tiles of 128)
#define NDEAD_ 67584  // NP_*E_

typedef unsigned short u16;
typedef __attribute__((ext_vector_type(8))) short short8;
typedef __attribute__((ext_vector_type(4))) short short4v;
typedef __attribute__((ext_vector_type(4))) float floatx4;

// HW RNE f32->bf16 via v_cvt_pk_bf16_f32. Self-pair form is operand-order-proof.
__device__ __forceinline__ u16 f2bf(float x) {
    unsigned r;
    asm("v_cvt_pk_bf16_f32 %0, %1, %1" : "=v"(r) : "v"(x));
    return (u16)r;
}
__device__ __forceinline__ float bf2f(u16 h) {
    return __uint_as_float(((unsigned)h) << 16);
}

// global -> LDS direct DMA, 16B per lane. LDS dest linear (uniform + lane*16);
// global src per-lane (carries the swizzle).
typedef __attribute__((address_space(1))) const void* gp_t;
typedef __attribute__((address_space(3))) void* lp_t;
__device__ __forceinline__ void gload16(const void* g, void* l) {
    __builtin_amdgcn_global_load_lds((gp_t)g, (lp_t)l, 16, 0, 0);
}

// Inline-asm register loads: keeps the VMEM FIFO under OUR control so counted
// vmcnt(N) waits work.
__device__ __forceinline__ floatx4 ld_f4(const float* p) {
    floatx4 r;
    asm volatile("global_load_dwordx4 %0, %1, off" : "=&v"(r) : "v"(p));
    return r;
}
__device__ __forceinline__ short8 ld_s8(const u16* p) {
    short8 r;
    asm volatile("global_load_dwordx4 %0, %1, off" : "=&v"(r) : "v"(p));
    return r;
}
// Counted waits that "launder" the prefetch registers: creates a dataflow edge
// load -> wait -> use, so no use can be scheduled before the wait (rule #18).
// CRITICAL: the laundered arrays are STATIC named sets; they are never copied,
// so no register with a pending load is ever read or reallocated (round-3 bug).
template<int N>
__device__ __forceinline__ void wait_vm_f(floatx4 (&a)[4]) {
    asm volatile("s_waitcnt vmcnt(%4)"
                 : "+v"(a[0]), "+v"(a[1]), "+v"(a[2]), "+v"(a[3])
                 : "i"(N) : "memory");
}
template<int N>
__device__ __forceinline__ void wait_vm_s(short8 (&a)[4]) {
    asm volatile("s_waitcnt vmcnt(%4)"
                 : "+v"(a[0]), "+v"(a[1]), "+v"(a[2]), "+v"(a[3])
                 : "i"(N) : "memory");
}

// 16B-slot swizzle key per row: rows r, r+2 must land in different slots too
// (row stride 64B == half the 128B bank period) -> key = ((r>>1)^r)&3.
__device__ __forceinline__ int swzk(int r) { return ((r >> 1) ^ r) & 3; }

// ---------------------------------------------------------------------------
// K_bucket: sniff dead dtype, count pairs per type, build bucketed pair list.
// wsI layout: [0]=mode, [1..3]=cnt, [4..6]=ps, [8..10]=rs,
//             [16..16+PV)=pairIdx, then prb[PV]
// ---------------------------------------------------------------------------
__global__ void k_bucket(const unsigned* __restrict__ deadRaw,
                         const int* __restrict__ hete, int* __restrict__ wsI)
{
    __shared__ int fl[2];
    __shared__ int sc[3], cur[3], sps[3], srs[3];
    int tid = threadIdx.x;
    if (tid < 2) fl[tid] = 0;
    if (tid < 3) { sc[tid] = 0; cur[tid] = 0; }
    __syncthreads();
    int ni = 0, nf = 0;
    for (int i = tid; i < 1024; i += 256) {
        unsigned w = deadRaw[i];
        if (w > 1u) ni = 1;
        if (w != 0u && w != 0x3F800000u) nf = 1;
    }
    if (ni) atomicOr(&fl[0], 1);
    if (nf) atomicOr(&fl[1], 1);
    for (int p = tid; p < NP_; p += 256) atomicAdd(&sc[hete[p]], 1);
    __syncthreads();
    if (tid == 0) {
        int c0 = sc[0], c1 = sc[1], c2 = sc[2];
        int p1 = (c0 + 127) & ~127;
        int p2 = p1 + ((c1 + 127) & ~127);
        sps[0] = 0; sps[1] = p1; sps[2] = p2;
        int r1 = (22 * c0 + 127) & ~127;
        int r2 = r1 + ((22 * c1 + 127) & ~127);
        srs[0] = 0; srs[1] = r1; srs[2] = r2;
        wsI[0] = fl[0] ? (fl[1] ? 2 : 1) : 0;  // 0=int32,1=float32,2=byte
        wsI[1] = c0; wsI[2] = c1; wsI[3] = c2;
        wsI[4] = 0; wsI[5] = p1; wsI[6] = p2;
        wsI[8] = 0; wsI[9] = r1; wsI[10] = r2;
    }
    __syncthreads();
    int* pairIdx = wsI + 16;
    int* prb = pairIdx + PV_;
    for (int pv = tid; pv < PV_; pv += 256) pairIdx[pv] = -1;
    __syncthreads();
    for (int p = tid; p < NP_; p += 256) {
        int t = hete[p];
        int pos = atomicAdd(&cur[t], 1);
        pairIdx[sps[t] + pos] = p;
    }
    for (int pv = tid; pv < PV_; pv += 256) {
        int t = (pv >= sps[1]) + (pv >= sps[2]);
        prb[pv] = srs[t] + 22 * (pv - sps[t]);
    }
}

__global__ void k_deadmask(const void* __restrict__ dead,
                           const int* __restrict__ wsI, float* __restrict__ dm)
{
    int i = blockIdx.x * 256 + threadIdx.x;
    if (i >= NDEAD_) return;
    int mode = wsI[0];
    bool d;
    if (mode == 0)      d = ((const int*)dead)[i] != 0;
    else if (mode == 1) d = ((const float*)dead)[i] != 0.f;
    else                d = ((const unsigned char*)dead)[i] != 0;
    dm[i] = d ? 0.f : 1.f;
}

// rowObs[rv] = obs row index for virtual row, or -1 (padding OR dead -> zero A row)
__global__ void k_rowobs(const int* __restrict__ cnt, const int* __restrict__ ps,
                         const int* __restrict__ rs, const int* __restrict__ pairIdx,
                         const float* __restrict__ dm, int* __restrict__ rowObs)
{
    int rv = blockIdx.x * 256 + threadIdx.x;
    if (rv >= RV_) return;
    int t = (rv >= rs[1]) + (rv >= rs[2]);
    int local = rv - rs[t];
    int out = -1;
    if (local < 22 * cnt[t]) {
        int pl = local / 22;
        int e = local - pl * 22;
        int p = pairIdx[ps[t] + pl];
        if (p >= 0) {
            int oi = p * 22 + e;
            if (dm[oi] != 0.f) out = oi;
        }
    }
    rowObs[rv] = out;
}

// ---------------------------------------------------------------------------
// k_wconv (fused, all 8 weight matrices): W[t][k][n] fp32 -> hi/lo bf16 [t][n][k]
// ---------------------------------------------------------------------------
struct WCA {
    const float* W[8]; u16* Hi[8]; u16* Lo[8]; int K[8]; int bs[9];
};
__global__ __launch_bounds__(256) void k_wconv(WCA a)
{
    int blk = blockIdx.x;
    int s = 0;
#pragma unroll
    for (int i = 1; i < 8; ++i) if (blk >= a.bs[i]) s = i;
    int lb = blk - a.bs[s];
    int K = a.K[s];
    int K8 = K >> 3;
    int kc = lb % K8;
    int t  = lb / K8;
    int n  = threadIdx.x;
    const float* w = a.W[s] + (long)t * K * 256 + n;
    short8 hv, lv;
#pragma unroll
    for (int j = 0; j < 8; ++j) {
        float x = w[(long)(kc * 8 + j) * 256];
        u16 hh = f2bf(x);
        hv[j] = (short)hh;
        lv[j] = (short)f2bf(x - bf2f(hh));
    }
    long o = ((long)t * 256 + n) * K + kc * 8;
    *(short8*)(a.Hi[s] + o) = hv;
    *(short8*)(a.Lo[s] + o) = lv;
}

// ---------------------------------------------------------------------------
// MFMA GEMM, bf16x3 split: C = op(A) @ B[type] + bias[type], optional relu.
// Tile 128x128, BK=32, 256 threads, double-buffered LDS (64KB).
// 3-deep pipeline with COUNTED vmcnt (T4) exploiting the latency asymmetry:
//   B (weights, L2-resident, ~250cy): global_load_lds, 1 tile ahead.
//   A (activations, HBM, ~900cy): reg-staged 2 tiles ahead (regs = 3rd buffer).
// Per-wave VMEM FIFO per sub-iteration: [A(t+1):4 | B(t+1):4 | A(t+2):4].
//   after compute: vmcnt(8)  -> A(t+1) ready, ds_write it to LDS
//   before barrier: vmcnt(4) -> B(t+1) DMA landed; A(t+2) stays IN FLIGHT
// Main loop unrolled x2 (nt is always even: K % 64 == 0) so the two A-prefetch
// register sets have STATIC alternating roles -- no copies/renames of
// registers with pending loads (round-3 crash: rotating sets let the
// allocator reuse pending-load dest registers).
// Uniform tail via clamped prefetch indices; full drain before the epilogue.
// Swizzle (both-sides, rule #21): A global loads LINEAR, swizzle on ds_write
// + frag read. B swizzles the global source (gload_lds dest must be linear).
// OUTS 0: fp32 C. OUTS 1: C hi/lo bf16 staged through LDS, 16B stores.
// ---------------------------------------------------------------------------
struct GD {
    const void* Aa; const void* Ab;   // AMODE0: hi,lo u16; AMODE1: fp32, unused
    const u16* Bh; const u16* Bl;
    const float* bias;
    void* Ca; void* Cb;               // OUTS0: fp32, unused; OUTS1: hi,lo u16
    long lda; long ldc;
    int K; int coff;
};
struct GA4 { GD d[4]; };

template<int AMODE, bool RELU, int OUTS>
__global__ __launch_bounds__(256, 2) void k_mgemm(
    GA4 ga, const int* __restrict__ rowIdx, const int* __restrict__ starts)
{
    // 64KB: buffer b at smem + b*16384: Ah +0, Al +4096, Bh +8192, Bl +12288
    __shared__ short smem[32768];
    const int tid = threadIdx.x;
    const GD d = ga.d[blockIdx.z];
    const long rb = (long)blockIdx.x * 128;
    const int n0 = blockIdx.y * 128;
    const int t = (rb >= starts[0]) + (rb >= starts[1]);
    const int K = d.K;
    const long lda = d.lda;
    const u16* bhT = d.Bh + ((long)t * 256 + n0) * K;
    const u16* blT = d.Bl + ((long)t * 256 + n0) * K;
    const float* biasT = d.bias + (long)t * 256 + n0;

    const int cs = tid & 3;             // 16B slot within 64B row
    const int r0 = tid >> 2;            // AMODE0 A rows (0..63), r1 = 64+r0
    const int r1 = 64 + r0;

    // AMODE1 reg-stage mapping: 4 iters of 32 rows x 32 k
    const int ar = tid >> 3;            // 0..31
    const int ac = (tid & 7) * 4;       // 0..28
    long arow[4]; float amask[4];
    const float* Afp = (const float*)d.Aa;
    if (AMODE == 1) {
#pragma unroll
        for (int it = 0; it < 4; ++it) {
            int r = 32 * it + ar;
            int i0 = rowIdx[rb + r];
            amask[it] = (i0 < 0) ? 0.f : 1.f;
            arow[it] = (i0 < 0) ? 0 : (long)i0 * lda;
        }
    }
    const u16* ahT = (const u16*)d.Aa;
    const u16* alT = (const u16*)d.Ab;

    // wave tiling
    const int wave = tid >> 6;
    const int lane = tid & 63;
    const int wr = (wave >> 1) * 64;
    const int wc = (wave & 1) * 64;
    const int lm = lane & 15;
    const int quad = lane >> 4;

    auto issueB = [&](int b, int k0) {
        short* Bh = smem + b * 16384 + 8192;
        short* Bl = smem + b * 16384 + 12288;
#pragma unroll
        for (int i = 0; i < 2; ++i) {
            int c = i * 256 + tid;
            int r = c >> 2;
            long go = (long)r * K + k0 + ((cs ^ swzk(r)) << 3);
            gload16(bhT + go, &Bh[c << 3]);
            gload16(blT + go, &Bl[c << 3]);
        }
    };
    auto issueA1 = [&](int k0, floatx4 (&dst)[4]) {
#pragma unroll
        for (int it = 0; it < 4; ++it)
            dst[it] = ld_f4(Afp + arow[it] + k0 + ac);
    };
    auto issueA0 = [&](int k0, short8 (&dst)[4]) {
        dst[0] = ld_s8(ahT + (rb + r0) * lda + k0 + cs * 8);
        dst[1] = ld_s8(ahT + (rb + r1) * lda + k0 + cs * 8);
        dst[2] = ld_s8(alT + (rb + r0) * lda + k0 + cs * 8);
        dst[3] = ld_s8(alT + (rb + r1) * lda + k0 + cs * 8);
    };
    auto writeA1 = [&](int b, floatx4 (&src)[4]) {
        short* AhW = smem + b * 16384;
        short* AlW = AhW + 4096;
#pragma unroll
        for (int it = 0; it < 4; ++it) {
            short4v hv, lv;
#pragma unroll
            for (int e = 0; e < 4; ++e) {
                float x = src[it][e] * amask[it];
                u16 hh = f2bf(x);
                hv[e] = (short)hh;
                lv[e] = (short)f2bf(x - bf2f(hh));
            }
            int r = 32 * it + ar;
            int bs = (((ac >> 3) ^ swzk(r)) << 4) | ((ac & 4) << 1);
            *(short4v*)((char*)AhW + r * 64 + bs) = hv;
            *(short4v*)((char*)AlW + r * 64 + bs) = lv;
        }
    };
    auto writeA0 = [&](int b, short8 (&src)[4]) {
        short* AhW = smem + b * 16384;
        short* AlW = AhW + 4096;
        *(short8*)((char*)AhW + r0 * 64 + ((cs ^ swzk(r0)) << 4)) = src[0];
        *(short8*)((char*)AhW + r1 * 64 + ((cs ^ swzk(r1)) << 4)) = src[1];
        *(short8*)((char*)AlW + r0 * 64 + ((cs ^ swzk(r0)) << 4)) = src[2];
        *(short8*)((char*)AlW + r1 * 64 + ((cs ^ swzk(r1)) << 4)) = src[3];
    };

    floatx4 acc[4][4];
#pragma unroll
    for (int i = 0; i < 4; ++i)
#pragma unroll
        for (int j = 0; j < 4; ++j) acc[i][j] = (floatx4){0.f, 0.f, 0.f, 0.f};

    auto computeT = [&](int b) {
        const short* Ah = smem + b * 16384;
        const short* Al = Ah + 4096;
        const short* Bh = Ah + 8192;
        const short* Bl = Ah + 12288;
        short8 fah[4], fal[4];
#pragma unroll
        for (int i = 0; i < 4; ++i) {
            int m = wr + 16 * i + lm;
            int sl = (quad ^ swzk(m)) << 3;
            fah[i] = *(const short8*)&Ah[(m << 5) + sl];
            fal[i] = *(const short8*)&Al[(m << 5) + sl];
        }
        __builtin_amdgcn_s_setprio(1);
#pragma unroll
        for (int j = 0; j < 4; ++j) {
            int n = wc + 16 * j + lm;
            int sl = (quad ^ swzk(n)) << 3;
            short8 fbh = *(const short8*)&Bh[(n << 5) + sl];
            short8 fbl = *(const short8*)&Bl[(n << 5) + sl];
#pragma unroll
            for (int i = 0; i < 4; ++i) {
                acc[i][j] = __builtin_amdgcn_mfma_f32_16x16x32_bf16(fah[i], fbh, acc[i][j], 0, 0, 0);
                acc[i][j] = __builtin_amdgcn_mfma_f32_16x16x32_bf16(fal[i], fbh, acc[i][j], 0, 0, 0);
                acc[i][j] = __builtin_amdgcn_mfma_f32_16x16x32_bf16(fah[i], fbl, acc[i][j], 0, 0, 0);
            }
        }
        __builtin_amdgcn_s_setprio(0);
    };

    // Two STATIC A-prefetch register sets; roles alternate by sub-iteration
    // parity. A(k) lives in set k&1; consumed (ds_written) at sub-iter k-1.
    floatx4 fS0[4], fS1[4];
    short8  s0[4], s1[4];
    const int nt = K >> 5;              // always even (K % 64 == 0)

    // ---- prologue ----
    // A(0) -> set0; B(0) DMA; A(0) -> LDS buf0; A(1) -> set1 (left in flight)
    if (AMODE == 1) issueA1(0, fS0); else issueA0(0, s0);      // [A0:4]
    issueB(0, 0);                                              // [A0:4, B0:4]
    if (AMODE == 1) { wait_vm_f<4>(fS0); writeA1(0, fS0); }    // A0 done
    else            { wait_vm_s<4>(s0);  writeA0(0, s0); }
    if (AMODE == 1) issueA1(32, fS1); else issueA0(32, s1);    // [B0:4, A1:4]
    asm volatile("s_waitcnt vmcnt(4) lgkmcnt(0)" ::: "memory"); // B0 done, A1 flying
    __builtin_amdgcn_s_barrier();
    __builtin_amdgcn_sched_barrier(0);

    // ---- main loop, x2 unrolled: even consumes set1/issues set0; odd the
    // reverse. Clamped tail prefetch re-reads the last tile (harmless). ----
    for (int ti = 0; ti < nt; ti += 2) {
        {   // even sub-iter: compute buf0
            const int kB = ((ti + 1 < nt) ? ti + 1 : nt - 1) << 5;
            const int kA = ((ti + 2 < nt) ? ti + 2 : nt - 1) << 5;
            issueB(1, kB);
            if (AMODE == 1) issueA1(kA, fS0); else issueA0(kA, s0);
            computeT(0);
            if (AMODE == 1) { wait_vm_f<8>(fS1); writeA1(1, fS1); }
            else            { wait_vm_s<8>(s1);  writeA0(1, s1); }
            asm volatile("s_waitcnt vmcnt(4) lgkmcnt(0)" ::: "memory");
            __builtin_amdgcn_s_barrier();
            __builtin_amdgcn_sched_barrier(0);
        }
        {   // odd sub-iter: compute buf1
            const int kB = ((ti + 2 < nt) ? ti + 2 : nt - 1) << 5;
            const int kA = ((ti + 3 < nt) ? ti + 3 : nt - 1) << 5;
            issueB(0, kB);
            if (AMODE == 1) issueA1(kA, fS1); else issueA0(kA, s1);
            computeT(1);
            if (AMODE == 1) { wait_vm_f<8>(fS0); writeA1(0, fS0); }
            else            { wait_vm_s<8>(s0);  writeA0(0, s0); }
            asm volatile("s_waitcnt vmcnt(4) lgkmcnt(0)" ::: "memory");
            __builtin_amdgcn_s_barrier();
            __builtin_amdgcn_sched_barrier(0);
        }
    }
    // drain leftover clamped prefetches before reusing smem in the epilogue
    asm volatile("s_waitcnt vmcnt(0) lgkmcnt(0)" ::: "memory");
    __builtin_amdgcn_s_barrier();
    __builtin_amdgcn_sched_barrier(0);

    // ---- epilogue ----
    if (OUTS == 0) {
        float* C = (float*)d.Ca;
#pragma unroll
        for (int j = 0; j < 4; ++j) {
            int col = wc + 16 * j + lm;
            float bj = biasT[col];
#pragma unroll
            for (int i = 0; i < 4; ++i) {
                long rbase = rb + wr + 16 * i + quad * 4;
#pragma unroll
                for (int r = 0; r < 4; ++r) {
                    float vv = acc[i][j][r] + bj;
                    if (RELU) vv = fmaxf(vv, 0.f);
                    C[(rbase + r) * d.ldc + d.coff + n0 + col] = vv;
                }
            }
        }
    } else {
        // stage hi/lo C-tile through LDS, then 16B coalesced stores.
        u16* Chi = (u16*)smem;            // 128x128 u16 = 32KB
        u16* Clo = Chi + 16384;
#pragma unroll
        for (int j = 0; j < 4; ++j) {
            int col = wc + 16 * j + lm;
            float bj = biasT[col];
#pragma unroll
            for (int i = 0; i < 4; ++i) {
                int row0 = wr + 16 * i + quad * 4;
#pragma unroll
                for (int r = 0; r < 4; ++r) {
                    float vv = acc[i][j][r] + bj;
                    if (RELU) vv = fmaxf(vv, 0.f);
                    int row = row0 + r;
                    int cc = col ^ (((row >> 2) & 3) << 4);
                    u16 hh = f2bf(vv);
                    Chi[row * 128 + cc] = hh;
                    Clo[row * 128 + cc] = f2bf(vv - bf2f(hh));
                }
            }
        }
        asm volatile("s_waitcnt lgkmcnt(0)" ::: "memory");
        __builtin_amdgcn_s_barrier();
        __builtin_amdgcn_sched_barrier(0);
        u16* Ca = (u16*)d.Ca;
        u16* Cb = (u16*)d.Cb;
#pragma unroll
        for (int s = 0; s < 8; ++s) {
            int ch = s * 256 + tid;
            int row = ch >> 4;
            int gcol = (ch & 15) * 8;
            int lo = row * 128 + (gcol ^ (((row >> 2) & 3) << 4));
            short8 hv = *(const short8*)&Chi[lo];
            short8 lv = *(const short8*)&Clo[lo];
            long go = (rb + row) * d.ldc + d.coff + n0 + gcol;
            *(short8*)(Ca + go) = hv;
            *(short8*)(Cb + go) = lv;
        }
    }
}

// ---------------------------------------------------------------------------
// k_prep: per pair -- denom, v-pool, z-pool, assemble XF/XH (1536 each),
// written directly as bf16 hi/lo (pre-split for the head GEMMs).
// ---------------------------------------------------------------------------
__global__ __launch_bounds__(256) void k_prep(
    const int* __restrict__ pairIdx, const int* __restrict__ prb,
    const float* __restrict__ dm, const float* __restrict__ v,
    const float* __restrict__ obs,
    u16* __restrict__ XFh, u16* __restrict__ XFl,
    u16* __restrict__ XHh, u16* __restrict__ XHl)
{
    int pv = blockIdx.x, c = threadIdx.x;
    int p = pairIdx[pv];
    long xo = (long)pv * 1536;
    if (p < 0) {
        for (int s = 0; s < 6; ++s) {
            XFh[xo + s * 256 + c] = 0; XFl[xo + s * 256 + c] = 0;
            XHh[xo + s * 256 + c] = 0; XHl[xo + s * 256 + c] = 0;
        }
        return;
    }
    __shared__ float sw[22];
    if (c < 22) sw[c] = dm[p * 22 + c];
    __syncthreads();
    float denf = 0.f, denh = 0.f;
    for (int e = 1; e < 12; ++e)  denf += sw[e];
    for (int e = 12; e < 22; ++e) denh += sw[e];
    denf = 1.f / fmaxf(denf, 1.f);
    denh = 1.f / fmaxf(denh, 1.f);

    auto wsp = [&](u16* Hh, u16* Hl, long idx, float val) {
        u16 hh = f2bf(val);
        Hh[idx] = hh;
        Hl[idx] = f2bf(val - bf2f(hh));
    };

    long base = prb[pv];
    float vs = v[base * 256 + c];
    wsp(XFh, XFl, xo + c, vs);
    wsp(XHh, XHl, xo + c, vs);
    float af = 0.f, ah = 0.f;
    for (int e = 1; e < 12; ++e)  af += sw[e] * v[(base + e) * 256 + c];
    for (int e = 12; e < 22; ++e) ah += sw[e] * v[(base + e) * 256 + c];
    wsp(XFh, XFl, xo + 256 + c, af * denf);
    wsp(XHh, XHl, xo + 256 + c, ah * denh);
    const float* ob = obs + (long)p * 22 * 512;
    float w0 = sw[0];
    float z0 = ob[c] * w0;
    float z1 = ob[256 + c] * w0;
    wsp(XFh, XFl, xo + 512 + c, z0); wsp(XHh, XHl, xo + 512 + c, z0);
    wsp(XFh, XFl, xo + 768 + c, z1); wsp(XHh, XHl, xo + 768 + c, z1);
#pragma unroll
    for (int half = 0; half < 2; ++half) {
        int c2 = c + half * 256;
        float zf = 0.f, zh = 0.f;
        for (int e = 1; e < 12; ++e)  zf += sw[e] * ob[(long)e * 512 + c2];
        for (int e = 12; e < 22; ++e) zh += sw[e] * ob[(long)e * 512 + c2];
        wsp(XFh, XFl, xo + 1024 + c2, zf * denf);
        wsp(XHh, XHl, xo + 1024 + c2, zh * denh);
    }
}

// ---------------------------------------------------------------------------
// Final: L2 layer fused + logits + argmax + log-softmax + value dot; scatter.
// ---------------------------------------------------------------------------
__global__ __launch_bounds__(128) void k_final(
    const float* __restrict__ g1, const float* __restrict__ vV,
    const float* __restrict__ L2, const float* __restrict__ bL2,
    const float* __restrict__ L3, const float* __restrict__ bL3,
    const float* __restrict__ V2, const float* __restrict__ bV2,
    const int* __restrict__ pairIdx, const int* __restrict__ ps,
    float* __restrict__ out)
{
    int pv = blockIdx.x;
    int p = pairIdx[pv];
    if (p < 0) return;
    int c = threadIdx.x;
    int t = (pv >= ps[1]) + (pv >= ps[2]);

    __shared__ float sg1[256], sg2[128], sval[2];
    const float* g1p = g1 + (long)pv * 256;
    sg1[c] = g1p[c];
    sg1[c + 128] = g1p[c + 128];

    const float* vv = vV + (long)pv * 256;
    const float* v2t = V2 + t * 256;
    float s = vv[c] * v2t[c] + vv[c + 128] * v2t[c + 128];
    for (int off = 32; off; off >>= 1) s += __shfl_down(s, off);
    if ((c & 63) == 0) sval[c >> 6] = s;
    __syncthreads();

    const float* l2 = L2 + (long)t * 256 * 128 + c;
    float a = bL2[t * 128 + c];
#pragma unroll 8
    for (int k = 0; k < 256; ++k) a = fmaf(sg1[k], l2[(long)k * 128], a);
    sg2[c] = fmaxf(a, 0.f);
    __syncthreads();

    if (c < 64) {
        float lg = -3.0e38f;
        if (c < 21) {
            const float* l3t = L3 + (long)t * 128 * 21 + c;
            float acc = bL3[t * 21 + c];
            for (int k = 0; k < 128; ++k) acc = fmaf(sg2[k], l3t[k * 21], acc);
            lg = acc;
        }
        float mv = lg; int mi = (c < 21) ? c : 9999;
        for (int off = 32; off; off >>= 1) {
            float ov = __shfl_down(mv, off);
            int oi = __shfl_down(mi, off);
            if (ov > mv || (ov == mv && oi < mi)) { mv = ov; mi = oi; }
        }
        mv = __shfl(mv, 0); mi = __shfl(mi, 0);
        float e = (c < 21) ? expf(lg - mv) : 0.f;
        for (int off = 32; off; off >>= 1) e += __shfl_down(e, off);
        if (c == 0) {
            out[p] = (float)mi;
            out[NP_ + p] = sval[0] + sval[1] + bV2[t];
            out[2 * NP_ + p] = -logf(e);
        }
    }
}

// ---------------------------------------------------------------------------
extern "C" void kernel_launch(void* const* d_in, const int* in_sizes, int n_in,
                              void* d_out, int out_size, void* d_ws, size_t ws_size,
                              hipStream_t stream)
{
    const float* obs = (const float*)d_in[0];
    const int* hete = (const int*)d_in[1];
    const void* dead = d_in[2];
    const float* W1 = (const float*)d_in[3];  const float* b1 = (const float*)d_in[4];
    const float* W2 = (const float*)d_in[5];  const float* b2 = (const float*)d_in[6];
    const float* WCf = (const float*)d_in[7]; const float* bCf = (const float*)d_in[8];
    const float* WMf = (const float*)d_in[9]; const float* bMf = (const float*)d_in[10];
    const float* WCh = (const float*)d_in[11]; const float* bCh = (const float*)d_in[12];
    const float* WMh = (const float*)d_in[13]; const float* bMh = (const float*)d_in[14];
    const float* L1 = (const float*)d_in[15]; const float* bL1 = (const float*)d_in[16];
    const float* L2 = (const float*)d_in[17]; const float* bL2 = (const float*)d_in[18];
    const float* L3 = (const float*)d_in[19]; const float* bL3 = (const float*)d_in[20];
    const float* V1 = (const float*)d_in[21]; const float* bV1 = (const float*)d_in[22];
    const float* V2 = (const float*)d_in[23]; const float* bV2 = (const float*)d_in[24];
    float* out = (float*)d_out;

    // ---- workspace carve-up (identical footprint to previous version) ----
    int* wsI = (int*)d_ws;
    int* pairIdx = wsI + 16;
    int* prb = pairIdx + PV_;
    int* rowObs = prb + PV_;
    long fbase = ((16L + PV_ + PV_ + RV_) + 63) & ~63L;
    float* wsF = (float*)d_ws;
    float* dm = wsF + fbase;
    float* cur = dm + NDEAD_;
    auto allocUS = [&](long K) { u16* p = (u16*)cur; cur += (3L * 256 * K) / 2; return p; };
    u16* W1h = allocUS(512);  u16* W1l = allocUS(512);
    u16* W2h = allocUS(256);  u16* W2l = allocUS(256);
    u16* WCfh = allocUS(512); u16* WCfl = allocUS(512);
    u16* WChh = allocUS(512); u16* WChl = allocUS(512);
    u16* WMfh = allocUS(1536); u16* WMfl = allocUS(1536);
    u16* WMhh = allocUS(1536); u16* WMhl = allocUS(1536);
    u16* L1h = allocUS(512);  u16* L1l = allocUS(512);
    u16* V1h = allocUS(512);  u16* V1l = allocUS(512);
    float* regA = cur;                               // RV_*256 floats
    float* regB = regA + (long)RV_ * 256;            // RV_*256 floats

    // regA overlays: h1 (hi/lo) for P1 phase, then XF/XH (hi/lo) for heads
    u16* h1h = (u16*)regA;
    u16* h1l = h1h + (long)RV_ * 256;                // ends exactly at regB
    u16* XFh = (u16*)regA;
    u16* XFl = XFh + (long)PV_ * 1536;
    u16* XHh = XFl + (long)PV_ * 1536;
    u16* XHl = XHh + (long)PV_ * 1536;
    // regB overlays: v fp32, then vC/vM (hi/lo) + g1/vV fp32
    float* v = regB;
    u16* vCh = (u16*)regB;
    u16* vCl = vCh + (long)PV_ * 512;
    u16* vMh = vCl + (long)PV_ * 512;
    u16* vMl = vMh + (long)PV_ * 512;
    float* g1 = (float*)(vMl + (long)PV_ * 512);
    float* vV = g1 + (long)PV_ * 256;

    // ---- bookkeeping ----
    k_bucket<<<1, 256, 0, stream>>>((const unsigned*)dead, hete, wsI);
    k_deadmask<<<264, 256, 0, stream>>>(dead, wsI, dm);
    k_rowobs<<<266, 256, 0, stream>>>(wsI + 1, wsI + 4, wsI + 8, pairIdx, dm, rowObs);

    // ---- weight conversion: single fused launch ----
    {
        WCA wa;
        const float* Ws[8] = {W1, W2, WCf, WCh, WMf, WMh, L1, V1};
        u16* His[8] = {W1h, W2h, WCfh, WChh, WMfh, WMhh, L1h, V1h};
        u16* Los[8] = {W1l, W2l, WCfl, WChl, WMfl, WMhl, L1l, V1l};
        int Ks[8] = {512, 256, 512, 512, 1536, 1536, 512, 512};
        int acc_b = 0; wa.bs[0] = 0;
        for (int i = 0; i < 8; ++i) {
            wa.W[i] = Ws[i]; wa.Hi[i] = His[i]; wa.Lo[i] = Los[i]; wa.K[i] = Ks[i];
            acc_b += 3 * Ks[i] / 8; wa.bs[i + 1] = acc_b;
        }
        k_wconv<<<acc_b, 256, 0, stream>>>(wa);
    }

    GA4 g;
    auto setd = [&](int i, const void* Aa, const void* Ab, const u16* Bh_, const u16* Bl_,
                    const float* bias, void* Ca, void* Cb, long lda_, long ldc_, int K_, int coff_) {
        g.d[i] = GD{Aa, Ab, Bh_, Bl_, bias, Ca, Cb, lda_, ldc_, K_, coff_};
    };

    // ---- phase 1a: h1 = relu(obs@W1+b1), output pre-split hi/lo ----
    for (int i = 0; i < 4; ++i)
        setd(i, obs, nullptr, W1h, W1l, b1, h1h, h1l, 512, 256, 512, 0);
    k_mgemm<1, true, 1><<<dim3(RV_ / 128, 2, 1), 256, 0, stream>>>(g, rowObs, wsI + 9);

    // ---- phase 1b: v = h1@W2+b2 (pure bf16) ----
    for (int i = 0; i < 4; ++i)
        setd(i, h1h, h1l, W2h, W2l, b2, v, nullptr, 256, 256, 256, 0);
    k_mgemm<0, false, 0><<<dim3(RV_ / 128, 2, 1), 256, 0, stream>>>(g, nullptr, wsI + 9);

    // ---- pair prep (writes XF/XH pre-split) ----
    k_prep<<<PV_, 256, 0, stream>>>(pairIdx, prb, dm, v, obs, XFh, XFl, XHh, XHl);

    // ---- heads H1+H2 fused into one z=4 launch (216 blocks) ----
    setd(0, XFh, XFl, WCfh, WCfl, bCf, vCh, vCl, 1536, 512, 512, 0);
    setd(1, XHh, XHl, WChh, WChl, bCh, vCh, vCl, 1536, 512, 512, 256);
    setd(2, XFh, XFl, WMfh, WMfl, bMf, vMh, vMl, 1536, 512, 1536, 0);
    setd(3, XHh, XHl, WMhh, WMhl, bMh, vMh, vMl, 1536, 512, 1536, 256);
    k_mgemm<0, true, 1><<<dim3(PV_ / 128, 2, 4), 256, 0, stream>>>(g, nullptr, wsI + 5);

    // ---- H3: g1 = relu(vC@L1); vV = relu(vM@V1) ----
    setd(0, vCh, vCl, L1h, L1l, bL1, g1, nullptr, 512, 256, 512, 0);
    setd(1, vMh, vMl, V1h, V1l, bV1, vV, nullptr, 512, 256, 512, 0);
    setd(2, vCh, vCl, L1h, L1l, bL1, g1, nullptr, 512, 256, 512, 0);
    setd(3, vCh, vCl, L1h, L1l, bL1, g1, nullptr, 512, 256, 512, 0);
    k_mgemm<0, true, 0><<<dim3(PV_ / 128, 2, 2), 256, 0, stream>>>(g, nullptr, wsI + 5);

    k_final<<<PV_, 128, 0, stream>>>(g1, vV, L2, bL2, L3, bL3, V2, bV2,
                                     pairIdx, wsI + 4, out);
    (void)in_sizes; (void)n_in; (void)out_size; (void)ws_size;
}